// Round 6
// baseline (1905.584 us; speedup 1.0000x reference)
//
#include <hip/hip_runtime.h>
#include <math.h>

// Problem constants (fixed by setup_inputs)
#define E_N 100000
#define D_N 300
#define R_N 1000
#define T_N 10000
#define K_N 25
#define DP  320      // padded D (multiple of 32)
#define KD  960      // padded 3D
#define BM  64
#define NT  1563     // ceil(E_N/BM)
#define TPB 3        // tiles per block; grid = 521 (521*3 = 1563 exactly)

typedef __attribute__((ext_vector_type(8))) short bf16x8;
typedef __attribute__((ext_vector_type(4))) float f32x4;

__device__ __forceinline__ float bf2f(unsigned short h){
  union{ unsigned int u; float f; } c; c.u = ((unsigned int)h)<<16; return c.f;
}
__device__ __forceinline__ unsigned short f2bf(float f){
  union{ float f; unsigned int u; } c; c.f = f;
  unsigned int u = c.u + 0x7FFFu + ((c.u>>16)&1u);   // RNE
  return (unsigned short)(u>>16);
}
__device__ __forceinline__ unsigned int pack2(float lo, float hi){
  return ((unsigned int)f2bf(hi)<<16) | f2bf(lo);
}

// ---------------- workspace layout (bytes) ----------------
// 3-buffer rotation, no in-place GEMM:
// B0=emb->gcn1->hw2->node, B1=h->gcn2, B2=hw1->hg1
static constexpr size_t OFF_B0    = 0;                         // 64MB
static constexpr size_t OFF_B1    = 64000000;                  // 64MB
static constexpr size_t OFF_B2    = 128000000;                 // 64MB
static constexpr size_t OFF_RFWD  = 192000000;                 // R*640*2 bf16 = 1.28MB
static constexpr size_t OFF_WTKG  = OFF_RFWD + 2400000;
static constexpr size_t OFF_WTW1  = OFF_WTKG + 204800;
static constexpr size_t OFF_WTW2  = OFF_WTW1 + 204800;
static constexpr size_t OFF_WTDN  = OFF_WTW2 + 204800;         // [320,960] bf16 transposed
static constexpr size_t OFF_BIASP = OFF_WTDN + 614400;
static constexpr size_t OFF_BGP   = OFF_BIASP + 1280;
static constexpr size_t OFF_PTRHR = OFF_BGP + 1280;
static constexpr size_t OFF_PTRTR = OFF_PTRHR + 4096;
static constexpr size_t OFF_PTRER = OFF_PTRTR + 4096;
static constexpr size_t OFF_PTRADJ= OFF_PTRER + 400896;
static constexpr size_t OFF_CURHR = OFF_PTRADJ + 400896;       // cursors contiguous: 1 memset
static constexpr size_t OFF_CURTR = OFF_CURHR + 4096;
static constexpr size_t OFF_CURER = OFF_CURTR + 4096;
static constexpr size_t OFF_CURADJ= OFF_CURER + 400896;
static constexpr size_t SZ_CURALL = 4096+4096+400896+400896;
static constexpr size_t OFF_SCHR  = OFF_CURADJ + 400896;
static constexpr size_t OFF_SVHR  = OFF_SCHR + 1200000;
static constexpr size_t OFF_SCTR  = OFF_SVHR + 1200000;
static constexpr size_t OFF_SVTR  = OFF_SCTR + 1200000;
static constexpr size_t OFF_SCER  = OFF_SVTR + 1200000;
static constexpr size_t OFF_SVER  = OFF_SCER + 1200000;
static constexpr size_t OFF_SCADJ = OFF_SVER + 1200000;
static constexpr size_t OFF_SVADJ = OFF_SCADJ + 2400000;
static constexpr size_t OFF_PART  = OFF_SVADJ + 2400000;
static constexpr size_t OFF_BSUM  = OFF_PART + 40000;          // 256 ints

// ---------------- weight prep ----------------
__global__ void k_prep_sq(const float* kg, const float* w1, const float* w2,
                          unsigned short* wtKG, unsigned short* wtW1, unsigned short* wtW2){
  int n = blockIdx.x, which = blockIdx.y, k = threadIdx.x;
  const float* src = which==0 ? kg : (which==1 ? w1 : w2);
  unsigned short* dst = which==0 ? wtKG : (which==1 ? wtW1 : wtW2);
  float v = (n < D_N && k < D_N) ? src[k*D_N + n] : 0.f;
  dst[(size_t)n*DP + k] = f2bf(v);
}

// DenseP_t[n][k]: k<300 -> Dense[k][n]; 320<=k<920 -> Dense[k-20][n]; else 0
__global__ void k_prep_dense(const float* dn, unsigned short* wt){
  int n = blockIdx.x, t = threadIdx.x;
  for(int k=t; k<KD; k+=320){
    int ko = (k < D_N) ? k : ((k >= DP && k < 920) ? k-20 : -1);
    float v = (n < D_N && ko >= 0) ? dn[(size_t)ko*D_N + n] : 0.f;
    wt[(size_t)n*KD + k] = f2bf(v);
  }
}

__global__ void k_prep_bias(const float* bias, const float* bg, float* biasP, float* bgP){
  int t = threadIdx.x;
  biasP[t] = (t < D_N) ? bias[t] : 0.f;
  bgP[t]   = (t < D_N) ? bg[t]   : 0.f;
}

// ---------------- emb normalize -> bf16 padded (wave-per-row, float4) ----------------
__global__ __launch_bounds__(256) void k_normalize(const float* __restrict__ w,
                                                   unsigned short* __restrict__ embb){
  int wv = threadIdx.x >> 6, lane = threadIdx.x & 63;
  int e = blockIdx.x*4 + wv;                      // grid = E/4
  const float4* row = (const float4*)(w + (size_t)e*D_N);   // 1200B rows, 16B aligned
  float4 x0 = row[lane];
  float4 x1 = make_float4(0.f,0.f,0.f,0.f);
  if(lane < 11) x1 = row[64 + lane];              // floats 256..299
  float s = x0.x*x0.x + x0.y*x0.y + x0.z*x0.z + x0.w*x0.w
          + x1.x*x1.x + x1.y*x1.y + x1.z*x1.z + x1.w*x1.w;
  #pragma unroll
  for(int off=32; off; off>>=1) s += __shfl_xor(s, off);
  float rn = rsqrtf(s);
  unsigned short* orow = embb + (size_t)e*DP;
  uint2 o0; o0.x = pack2(x0.x*rn, x0.y*rn); o0.y = pack2(x0.z*rn, x0.w*rn);
  *(uint2*)(orow + lane*4) = o0;
  if(lane < 16){
    uint2 o1 = make_uint2(0u,0u);
    if(lane < 11){ o1.x = pack2(x1.x*rn, x1.y*rn); o1.y = pack2(x1.z*rn, x1.w*rn); }
    *(uint2*)(orow + 256 + lane*4) = o1;          // cols 256..319 (incl. zero pad)
  }
}

// ---------------- CSR build (counting sort) ----------------
__global__ void k_count(const int* hr, const int* tr, const int* er, const int* ad,
                        int* cHR, int* cTR, int* cER, int* cAD){
  int i = blockIdx.x*256 + threadIdx.x;
  if(i < 300000)       atomicAdd(&cHR[hr[i]], 1);
  else if(i < 600000)  atomicAdd(&cTR[tr[i-300000]], 1);
  else if(i < 900000)  atomicAdd(&cER[er[i-600000]], 1);
  else if(i < 1500000) atomicAdd(&cAD[ad[i-900000]], 1);
}

__global__ void k_scan_small(int* cHR, int* cTR, int* pHR, int* pTR){
  __shared__ int s[1024];
  int t = threadIdx.x;
  for(int w=0; w<2; w++){
    int* cnt = w ? cTR : cHR; int* ptr = w ? pTR : pHR;
    int c = (t < R_N) ? cnt[t] : 0;
    s[t] = c; __syncthreads();
    for(int off=1; off<1024; off<<=1){
      int v = (t>=off) ? s[t-off] : 0; __syncthreads();
      s[t] += v; __syncthreads();
    }
    int excl = s[t] - c;
    if(t < R_N){ ptr[t] = excl; cnt[t] = excl; }
    if(t == R_N-1) ptr[R_N] = s[t];
    __syncthreads();
  }
}

__global__ void k_scan_part(const int* cER, const int* cAD, int* pER, int* pAD, int* bsum){
  int which = blockIdx.y;
  const int* cnt = which ? cAD : cER;
  int* ptr = which ? pAD : pER;
  __shared__ int s[1024];
  int g = blockIdx.x, t = threadIdx.x, i = g*1024 + t;
  int c = (i < E_N) ? cnt[i] : 0;
  s[t] = c; __syncthreads();
  for(int off=1; off<1024; off<<=1){
    int v = (t>=off) ? s[t-off] : 0; __syncthreads();
    s[t] += v; __syncthreads();
  }
  if(i < E_N) ptr[i] = s[t] - c;
  if(t == 1023) bsum[which*128 + g] = s[1023];
}

__global__ void k_scan_mid(int* bsum, int* pER, int* pAD){
  __shared__ int s[128];
  int t = threadIdx.x;
  for(int w=0; w<2; w++){
    int v = (t < 98) ? bsum[w*128 + t] : 0;
    s[t] = v; __syncthreads();
    for(int off=1; off<128; off<<=1){
      int u = (t>=off) ? s[t-off] : 0; __syncthreads();
      s[t] += u; __syncthreads();
    }
    if(t < 98) bsum[w*128 + t] = s[t] - v;
    if(t == 97){ int* p = w ? pAD : pER; p[E_N] = s[97]; }
    __syncthreads();
  }
}

__global__ void k_scan_add(const int* bsum, int* pER, int* pAD, int* curER, int* curAD){
  int which = blockIdx.y;
  int* ptr = which ? pAD : pER;
  int* cur = which ? curAD : curER;
  int g = blockIdx.x, i = g*1024 + threadIdx.x;
  if(i < E_N){ int v = ptr[i] + bsum[which*128 + g]; ptr[i] = v; cur[i] = v; }
}

__global__ void k_scatter(const int* hr_r, const int* hr_c, const float* hr_v,
                          const int* tr_r, const int* tr_c, const float* tr_v,
                          const int* er_r, const int* er_c, const float* er_v,
                          const int* ad_r, const int* ad_c, const float* ad_v,
                          int* cHR, int* cTR, int* cER, int* cAD,
                          int* scHR, float* svHR, int* scTR, float* svTR,
                          int* scER, float* svER, int* scAD, float* svAD){
  int i = blockIdx.x*256 + threadIdx.x;
  if(i < 300000){ int p=atomicAdd(&cHR[hr_r[i]],1); scHR[p]=hr_c[i]; svHR[p]=hr_v[i]; }
  else if(i < 600000){ int j=i-300000; int p=atomicAdd(&cTR[tr_r[j]],1); scTR[p]=tr_c[j]; svTR[p]=tr_v[j]; }
  else if(i < 900000){ int j=i-600000; int p=atomicAdd(&cER[er_r[j]],1); scER[p]=er_c[j]; svER[p]=er_v[j]; }
  else if(i < 1500000){ int j=i-900000; int p=atomicAdd(&cAD[ad_r[j]],1); scAD[p]=ad_c[j]; svAD[p]=ad_v[j]; }
}

// ---------------- spmm's (CSR per-row, no atomics) ----------------
// rfwdb[r][off..off+300) bf16 = sum val * emb[col]
__global__ __launch_bounds__(256) void k_spmm_rel(
    const int* __restrict__ ptr, const int* __restrict__ scol, const float* __restrict__ sval,
    const unsigned short* __restrict__ embb, unsigned short* __restrict__ rfwdb, int off){
  int w = threadIdx.x >> 6, lane = threadIdx.x & 63;
  int r = blockIdx.x*2 + (w>>1);
  int half = w & 1;
  int elem = half*160 + 4*lane;
  bool act = (lane < 40) && (elem < 300);
  int b = ptr[r], e2 = ptr[r+1];
  float a0=0.f, a1=0.f, a2=0.f, a3=0.f;
  if(act){
    const unsigned short* base = embb + elem;
    int j = b;
    for(; j+4 <= e2; j += 4){
      int c0=scol[j], c1=scol[j+1], c2=scol[j+2], c3=scol[j+3];
      float v0=sval[j], v1=sval[j+1], v2=sval[j+2], v3=sval[j+3];
      uint2 x0 = *(const uint2*)(base + (size_t)c0*DP);
      uint2 x1 = *(const uint2*)(base + (size_t)c1*DP);
      uint2 x2 = *(const uint2*)(base + (size_t)c2*DP);
      uint2 x3 = *(const uint2*)(base + (size_t)c3*DP);
      a0 += v0*bf2f(x0.x&0xFFFF) + v1*bf2f(x1.x&0xFFFF) + v2*bf2f(x2.x&0xFFFF) + v3*bf2f(x3.x&0xFFFF);
      a1 += v0*bf2f(x0.x>>16)    + v1*bf2f(x1.x>>16)    + v2*bf2f(x2.x>>16)    + v3*bf2f(x3.x>>16);
      a2 += v0*bf2f(x0.y&0xFFFF) + v1*bf2f(x1.y&0xFFFF) + v2*bf2f(x2.y&0xFFFF) + v3*bf2f(x3.y&0xFFFF);
      a3 += v0*bf2f(x0.y>>16)    + v1*bf2f(x1.y>>16)    + v2*bf2f(x2.y>>16)    + v3*bf2f(x3.y>>16);
    }
    for(; j < e2; j++){
      int c = scol[j]; float v = sval[j];
      uint2 x = *(const uint2*)(base + (size_t)c*DP);
      a0 += v*bf2f(x.x&0xFFFF); a1 += v*bf2f(x.x>>16);
      a2 += v*bf2f(x.y&0xFFFF); a3 += v*bf2f(x.y>>16);
    }
    uint2 o;
    o.x = pack2(a0, a1);
    o.y = pack2(a2, a3);
    *(uint2*)&rfwdb[(size_t)r*640 + off + elem] = o;
  }
}

// gcn[e] = relu(sum val * x[col]); wave-per-row, 16B lanes (0..39), 2-way j-unroll (MLP)
__global__ __launch_bounds__(256) void k_spmm_adj(
    const int* __restrict__ ptr, const int* __restrict__ scol, const float* __restrict__ sval,
    const unsigned short* __restrict__ xin, unsigned short* __restrict__ out){
  int w = threadIdx.x >> 6, lane = threadIdx.x & 63;
  int e = blockIdx.x*4 + w;
  int b = ptr[e], en = ptr[e+1];
  if(lane < 40){
    float acc0[8], acc1[8];
    #pragma unroll
    for(int i=0;i<8;i++){ acc0[i]=0.f; acc1[i]=0.f; }
    const unsigned short* base = xin + lane*8;
    int j = b;
    for(; j+2 <= en; j += 2){
      int c0 = scol[j], c1 = scol[j+1];
      float v0 = sval[j], v1 = sval[j+1];
      bf16x8 x0 = *(const bf16x8*)(base + (size_t)c0*DP);
      bf16x8 x1 = *(const bf16x8*)(base + (size_t)c1*DP);
      #pragma unroll
      for(int i=0;i<8;i++){ acc0[i] += v0 * bf2f((unsigned short)x0[i]);
                            acc1[i] += v1 * bf2f((unsigned short)x1[i]); }
    }
    if(j < en){
      int c = scol[j]; float v = sval[j];
      bf16x8 x = *(const bf16x8*)(base + (size_t)c*DP);
      #pragma unroll
      for(int i=0;i<8;i++) acc0[i] += v * bf2f((unsigned short)x[i]);
    }
    bf16x8 o;
    #pragma unroll
    for(int i=0;i<8;i++) o[i] = (short)f2bf(fmaxf(acc0[i]+acc1[i], 0.f));
    *(bf16x8*)&out[(size_t)e*DP + lane*8] = o;
  }
}

// ---------------- MFMA GEMM, M-pipelined with register prefetch ----------------
// grid=521 blocks x TPB=3 consecutive 64-row tiles. Per tile:
//   [mode1: er-stages build nb halves in LDS, kloop kb=320/640]
//   sync; ds_write prefetched A1 regs -> LDS (XOR swizzle); sync;
//   issue register prefetch of NEXT tile's 40KB  <-- HBM busy during compute
//   kloop kb=0; epilogue (res for modes 1/2 read from LDS = A1-tile).
// NOTE: bbase[] already includes the quad*8 k-offset — do NOT re-add in kloop
// (rnd5 bug: double-added quad*8 corrupted B frags for quads 1..3).
__device__ __forceinline__ void gemm_kloop(f32x4 acc[4][5], const unsigned short (*As)[DP],
    const unsigned short* const* bbase, int kb, int quad, int l16){
  #pragma unroll 2
  for(int kk=0; kk<DP; kk+=32){
    bf16x8 af[4], bfr[5];
    #pragma unroll
    for(int mf=0; mf<4; mf++){
      int pc = ((kk>>3) + quad) ^ (l16 & 7);
      af[mf] = *(const bf16x8*)&As[mf*16 + l16][pc*8];
    }
    #pragma unroll
    for(int nf=0; nf<5; nf++)
      bfr[nf] = *(const bf16x8*)(bbase[nf] + kb + kk);
    #pragma unroll
    for(int mf=0; mf<4; mf++)
      #pragma unroll
      for(int nf=0; nf<5; nf++)
        acc[mf][nf] = __builtin_amdgcn_mfma_f32_16x16x32_bf16(af[mf], bfr[nf], acc[mf][nf], 0, 0, 0);
  }
}

__global__ __launch_bounds__(256,2) void k_gemm(
    const unsigned short* __restrict__ A1,     // [E, DP]
    const unsigned short* __restrict__ Bt,     // [320, Kp] (n-major, k-contiguous)
    int Kp,
    const int* __restrict__ erPtr, const int* __restrict__ erCol, const float* __restrict__ erVal,
    const unsigned short* __restrict__ rfwdb,  // [R,640] bf16
    const float* __restrict__ biasP,
    const unsigned short* __restrict__ gcn,
    unsigned short* __restrict__ outp,
    int mode){
  __shared__ unsigned short As[BM][DP];        // 40KB, XOR-swizzled 16B chunks
  int tid = threadIdx.x;
  int wave = tid>>6, lane = tid&63, quad = lane>>4, l16 = lane&15;
  int t0 = blockIdx.x * TPB;

  // per-lane B base pointers (quad*8 k-offset INCLUDED here, only here)
  const unsigned short* bbase[5];
  #pragma unroll
  for(int nf=0; nf<5; nf++)
    bbase[nf] = Bt + (size_t)(wave*80 + nf*16 + l16)*Kp + quad*8;

  float breg[5];
  if(mode){
    #pragma unroll
    for(int nf=0; nf<5; nf++) breg[nf] = biasP[wave*80 + nf*16 + l16];
  }

  // preamble prefetch: tile t0 (40KB contiguous, 10x16B per thread)
  uint4 R[10];
  {
    const unsigned short* src = A1 + (size_t)t0*BM*DP;
    #pragma unroll
    for(int i=0; i<10; i++) R[i] = *(const uint4*)(src + (size_t)(tid + i*256)*8);
  }

  for(int t = t0; t < t0 + TPB; t++){
    int m0 = t*BM;
    f32x4 acc[4][5];
    #pragma unroll
    for(int mf=0; mf<4; mf++)
      #pragma unroll
      for(int nf=0; nf<5; nf++) acc[mf][nf] = (f32x4){0.f,0.f,0.f,0.f};

    if(mode == 1){
      // er stages FIRST so the A1 (residual) tile is in LDS at epilogue time
      for(int h=0; h<2; h++){
        __syncthreads();
        int halfOff = h*320;
        for(int rr=0; rr<16; rr++){
          int row = wave*16 + rr;
          int e = m0 + row;
          float a0[8], a1[8];
          #pragma unroll
          for(int i=0;i<8;i++){ a0[i]=0.f; a1[i]=0.f; }
          if(e < E_N && lane < 40){
            int jb = erPtr[e], je = erPtr[e+1];
            const unsigned short* gb = rfwdb + halfOff + lane*8;
            int j = jb;
            for(; j+2 <= je; j += 2){
              int c0=erCol[j], c1=erCol[j+1];
              float v0=erVal[j], v1=erVal[j+1];
              int p0=c0, p1=c1;
              if(c0 >= R_N){ p0 = c0-R_N; v0 = -v0; }
              if(c1 >= R_N){ p1 = c1-R_N; v1 = -v1; }
              bf16x8 x0 = *(const bf16x8*)(gb + (size_t)p0*640);
              bf16x8 x1 = *(const bf16x8*)(gb + (size_t)p1*640);
              #pragma unroll
              for(int i=0;i<8;i++){ a0[i] += v0*bf2f((unsigned short)x0[i]);
                                    a1[i] += v1*bf2f((unsigned short)x1[i]); }
            }
            if(j < je){
              int c=erCol[j]; float v=erVal[j];
              int p=c; if(c >= R_N){ p = c-R_N; v = -v; }
              bf16x8 x = *(const bf16x8*)(gb + (size_t)p*640);
              #pragma unroll
              for(int i=0;i<8;i++) a0[i] += v*bf2f((unsigned short)x[i]);
            }
          }
          if(lane < 40){
            bf16x8 o;
            #pragma unroll
            for(int i=0;i<8;i++) o[i] = (short)f2bf(a0[i]+a1[i]);
            int pc = lane ^ (row & 7);
            *(bf16x8*)&As[row][pc*8] = o;
          }
        }
        __syncthreads();
        gemm_kloop(acc, As, bbase, DP + halfOff, quad, l16);
      }
    }

    // A1 stage from prefetch registers
    __syncthreads();
    #pragma unroll
    for(int i=0; i<10; i++){
      int idx = tid + i*256;
      int row = idx / 40, colc = idx % 40;
      *(uint4*)&As[row][(colc ^ (row & 7))*8] = R[i];
    }
    __syncthreads();

    // prefetch NEXT tile while this tile computes
    if(t+1 < t0 + TPB){
      const unsigned short* src = A1 + (size_t)(t+1)*BM*DP;
      #pragma unroll
      for(int i=0; i<10; i++) R[i] = *(const uint4*)(src + (size_t)(tid + i*256)*8);
    }

    gemm_kloop(acc, As, bbase, 0, quad, l16);

    // epilogue: C/D layout col=lane&15, row=quad*4+i; res (modes 1/2) from LDS A1-tile
    #pragma unroll
    for(int mf=0; mf<4; mf++){
      #pragma unroll
      for(int nf=0; nf<5; nf++){
        int col = wave*80 + nf*16 + l16;
        int chk = col >> 3, sub = col & 7;
        #pragma unroll
        for(int i=0; i<4; i++){
          int rowl = mf*16 + quad*4 + i;
          int row = m0 + rowl;
          if(row >= E_N) continue;
          size_t idx = (size_t)row*DP + col;
          float c = acc[mf][nf][i];
          float o;
          if(mode == 0){
            o = c;
          } else {
            float resv = bf2f(As[rowl][(chk ^ (rowl & 7))*8 + sub]);
            if(mode == 1){
              o = resv + fmaxf(c + breg[nf], 0.f);
            } else {
              float tg = 1.f / (1.f + expf(-(c + breg[nf])));
              o = tg * bf2f(gcn[idx]) + (1.f - tg) * resv;
            }
          }
          outp[idx] = f2bf(o);
        }
      }
    }
  }
}

// ---------------- loss (dm fused; 2-way k interleave for gather MLP) ----------------
__global__ __launch_bounds__(256) void k_loss(const unsigned short* __restrict__ node,
                       const int* __restrict__ pl, const int* __restrict__ pr,
                       const int* __restrict__ nr, const int* __restrict__ nl,
                       const float* __restrict__ mask,
                       float* __restrict__ part){
  int t = blockIdx.x;
  int w = threadIdx.x >> 6, lane = threadIdx.x & 63;
  __shared__ float wsum[4];
  bool act = lane < 40;
  size_t lb = (size_t)pl[t]*DP, rb = (size_t)pr[t]*DP;
  float lv[8], rv[8];
  #pragma unroll
  for(int i=0;i<8;i++){ lv[i]=0.f; rv[i]=0.f; }
  if(act){
    bf16x8 L = *(const bf16x8*)&node[lb + lane*8];
    bf16x8 R = *(const bf16x8*)&node[rb + lane*8];
    #pragma unroll
    for(int i=0;i<8;i++){ lv[i]=bf2f((unsigned short)L[i]); rv[i]=bf2f((unsigned short)R[i]); }
  }
  // Dm from lv/rv (every wave computes; replaces separate k_dm kernel)
  float s = 0.f;
  #pragma unroll
  for(int i=0;i<8;i++) s += fabsf(lv[i] - rv[i]);
  #pragma unroll
  for(int off=32; off; off>>=1) s += __shfl_xor(s, off);
  float dm = s + 1.0f;   // + GAMMA

  float local = 0.f;
  for(int k=w; k<K_N; k+=8){
    int k2 = k + 4;
    bool h2 = k2 < K_N;
    int kb = h2 ? k2 : k;
    float s1a=0.f, s2a=0.f, s1b=0.f, s2b=0.f;
    if(act){
      size_t nrb  = (size_t)nr[t*K_N+k ]*DP, nlb  = (size_t)nl[t*K_N+k ]*DP;
      size_t nrb2 = (size_t)nr[t*K_N+kb]*DP, nlb2 = (size_t)nl[t*K_N+kb]*DP;
      bf16x8 X1 = *(const bf16x8*)&node[nrb  + lane*8];
      bf16x8 Y1 = *(const bf16x8*)&node[nlb  + lane*8];
      bf16x8 X2 = *(const bf16x8*)&node[nrb2 + lane*8];
      bf16x8 Y2 = *(const bf16x8*)&node[nlb2 + lane*8];
      #pragma unroll
      for(int i=0;i<8;i++){
        s1a += fabsf(lv[i] - bf2f((unsigned short)X1[i]));
        s2a += fabsf(bf2f((unsigned short)Y1[i]) - rv[i]);
        s1b += fabsf(lv[i] - bf2f((unsigned short)X2[i]));
        s2b += fabsf(bf2f((unsigned short)Y2[i]) - rv[i]);
      }
    }
    #pragma unroll
    for(int off=32; off; off>>=1){
      s1a += __shfl_xor(s1a, off); s2a += __shfl_xor(s2a, off);
      s1b += __shfl_xor(s1b, off); s2b += __shfl_xor(s2b, off);
    }
    if(lane==0){
      local += (fmaxf(dm - s1a, 0.f) + fmaxf(dm - s2a, 0.f)) * mask[t*K_N+k];
      if(h2) local += (fmaxf(dm - s1b, 0.f) + fmaxf(dm - s2b, 0.f)) * mask[t*K_N+k2];
    }
  }
  if(lane==0) wsum[w] = local;
  __syncthreads();
  if(threadIdx.x==0) part[t] = wsum[0]+wsum[1]+wsum[2]+wsum[3];
}

__global__ void k_reduce(const float* part, float* out){
  __shared__ float s[256];
  int t = threadIdx.x;
  float a = 0.f;
  for(int i=t; i<T_N; i+=256) a += part[i];
  s[t] = a; __syncthreads();
  for(int off=128; off; off>>=1){ if(t<off) s[t]+=s[t+off]; __syncthreads(); }
  if(t==0) out[0] = s[0]*0.5f;
}

// ---------------- driver ----------------
extern "C" void kernel_launch(void* const* d_in, const int* in_sizes, int n_in,
                              void* d_out, int out_size, void* d_ws, size_t ws_size,
                              hipStream_t stream){
  const float* Wemb = (const float*)d_in[0];
  const float* KG   = (const float*)d_in[1];
  const float* BG   = (const float*)d_in[2];
  const float* W1   = (const float*)d_in[3];
  const float* W2   = (const float*)d_in[4];
  const float* DN   = (const float*)d_in[5];
  const float* BI   = (const float*)d_in[6];
  const int* HRr = (const int*)d_in[7];  const int* HRc = (const int*)d_in[8];  const float* HRv = (const float*)d_in[9];
  const int* TRr = (const int*)d_in[10]; const int* TRc = (const int*)d_in[11]; const float* TRv = (const float*)d_in[12];
  const int* ERr = (const int*)d_in[13]; const int* ERc = (const int*)d_in[14]; const float* ERv = (const float*)d_in[15];
  const int* ADr = (const int*)d_in[16]; const int* ADc = (const int*)d_in[17]; const float* ADv = (const float*)d_in[18];
  const int* PL = (const int*)d_in[19]; const int* PR = (const int*)d_in[20];
  const int* NR = (const int*)d_in[21]; const int* NL = (const int*)d_in[22];
  const float* MASK = (const float*)d_in[23];
  char* ws = (char*)d_ws;

  unsigned short* B0 = (unsigned short*)(ws + OFF_B0);
  unsigned short* B1 = (unsigned short*)(ws + OFF_B1);
  unsigned short* B2 = (unsigned short*)(ws + OFF_B2);
  unsigned short* rfwdb = (unsigned short*)(ws + OFF_RFWD);
  unsigned short* wtKG = (unsigned short*)(ws + OFF_WTKG);
  unsigned short* wtW1 = (unsigned short*)(ws + OFF_WTW1);
  unsigned short* wtW2 = (unsigned short*)(ws + OFF_WTW2);
  unsigned short* wtDN = (unsigned short*)(ws + OFF_WTDN);
  float* biasP = (float*)(ws + OFF_BIASP);
  float* bgP   = (float*)(ws + OFF_BGP);
  int* pHR = (int*)(ws + OFF_PTRHR); int* pTR = (int*)(ws + OFF_PTRTR);
  int* pER = (int*)(ws + OFF_PTRER); int* pAD = (int*)(ws + OFF_PTRADJ);
  int* cHR = (int*)(ws + OFF_CURHR); int* cTR = (int*)(ws + OFF_CURTR);
  int* cER = (int*)(ws + OFF_CURER); int* cAD = (int*)(ws + OFF_CURADJ);
  int* scHR = (int*)(ws + OFF_SCHR); float* svHR = (float*)(ws + OFF_SVHR);
  int* scTR = (int*)(ws + OFF_SCTR); float* svTR = (float*)(ws + OFF_SVTR);
  int* scER = (int*)(ws + OFF_SCER); float* svER = (float*)(ws + OFF_SVER);
  int* scAD = (int*)(ws + OFF_SCADJ); float* svAD = (float*)(ws + OFF_SVADJ);
  float* part = (float*)(ws + OFF_PART);
  int* bsum   = (int*)(ws + OFF_BSUM);

  (void)hipMemsetAsync(ws + OFF_CURHR, 0, SZ_CURALL, stream);
  (void)hipMemsetAsync(ws + OFF_RFWD, 0, 1280000, stream);   // rfwdb incl. pad cols

  k_prep_sq<<<dim3(320,3), 320, 0, stream>>>(KG, W1, W2, wtKG, wtW1, wtW2);
  k_prep_dense<<<320, 320, 0, stream>>>(DN, wtDN);
  k_prep_bias<<<1, 320, 0, stream>>>(BI, BG, biasP, bgP);
  k_normalize<<<E_N/4, 256, 0, stream>>>(Wemb, B0);

  k_count<<<5860, 256, 0, stream>>>(HRr, TRr, ERr, ADr, cHR, cTR, cER, cAD);
  k_scan_small<<<1, 1024, 0, stream>>>(cHR, cTR, pHR, pTR);
  k_scan_part<<<dim3(98,2), 1024, 0, stream>>>(cER, cAD, pER, pAD, bsum);
  k_scan_mid<<<1, 128, 0, stream>>>(bsum, pER, pAD);
  k_scan_add<<<dim3(98,2), 1024, 0, stream>>>(bsum, pER, pAD, cER, cAD);
  k_scatter<<<5860, 256, 0, stream>>>(HRr,HRc,HRv, TRr,TRc,TRv, ERr,ERc,ERv, ADr,ADc,ADv,
                                      cHR,cTR,cER,cAD, scHR,svHR, scTR,svTR, scER,svER, scAD,svAD);

  k_spmm_rel<<<R_N/2, 256, 0, stream>>>(pHR, scHR, svHR, B0, rfwdb, 0);
  k_spmm_rel<<<R_N/2, 256, 0, stream>>>(pTR, scTR, svTR, B0, rfwdb, 300);

  const int GB = 521;   // x TPB=3 tiles = 1563
  // h = emb + relu([emb|nb] @ Dense + Bias):  B0 -> B1
  k_gemm<<<GB, 256, 0, stream>>>(B0, wtDN, KD, pER, scER, svER, rfwdb, biasP, nullptr, B1, 1);
  // hw1 = h@W1:  B1 -> B2
  k_gemm<<<GB, 256, 0, stream>>>(B1, wtW1, DP, nullptr, nullptr, nullptr, nullptr, nullptr, nullptr, B2, 0);
  // gcn1 = relu(adj @ hw1):  B2 -> B0
  k_spmm_adj<<<E_N/4, 256, 0, stream>>>(pAD, scAD, svAD, B2, B0);
  // hg1 = highway(h, gcn1):  A=B1, gcn=B0 -> B2
  k_gemm<<<GB, 256, 0, stream>>>(B1, wtKG, DP, nullptr, nullptr, nullptr, nullptr, bgP, B0, B2, 2);
  // hw2 = hg1@W2:  B2 -> B0
  k_gemm<<<GB, 256, 0, stream>>>(B2, wtW2, DP, nullptr, nullptr, nullptr, nullptr, nullptr, nullptr, B0, 0);
  // gcn2 = relu(adj @ hw2):  B0 -> B1
  k_spmm_adj<<<E_N/4, 256, 0, stream>>>(pAD, scAD, svAD, B0, B1);
  // node = highway(hg1, gcn2):  A=B2, gcn=B1 -> B0
  k_gemm<<<GB, 256, 0, stream>>>(B2, wtKG, DP, nullptr, nullptr, nullptr, nullptr, bgP, B1, B0, 2);

  k_loss<<<T_N, 256, 0, stream>>>(B0, PL, PR, NR, NL, MASK, part);
  k_reduce<<<1, 256, 0, stream>>>(part, (float*)d_out);
}

// Round 7
// 1332.516 us; speedup vs baseline: 1.4301x; 1.4301x over previous
//
#include <hip/hip_runtime.h>
#include <math.h>

// Problem constants (fixed by setup_inputs)
#define E_N 100000
#define D_N 300
#define R_N 1000
#define T_N 10000
#define K_N 25
#define DP  320      // padded D (multiple of 32)
#define KD  960      // padded 3D
#define BM  64
#define NT  1563     // ceil(E_N/BM); padded rows = NT*64 = 100032

typedef __attribute__((ext_vector_type(8))) short bf16x8;
typedef __attribute__((ext_vector_type(4))) float f32x4;

__device__ __forceinline__ float bf2f(unsigned short h){
  union{ unsigned int u; float f; } c; c.u = ((unsigned int)h)<<16; return c.f;
}
__device__ __forceinline__ unsigned short f2bf(float f){
  union{ float f; unsigned int u; } c; c.f = f;
  unsigned int u = c.u + 0x7FFFu + ((c.u>>16)&1u);   // RNE
  return (unsigned short)(u>>16);
}
__device__ __forceinline__ unsigned int pack2(float lo, float hi){
  return ((unsigned int)f2bf(hi)<<16) | f2bf(lo);
}

// ---------------- workspace layout (bytes) ----------------
// Buffers padded to 100032 rows so tile-1562 loads/stores stay in-buffer.
// B0: emb -> hg1 ; B1: h -> node ; B2: hw1 -> hw2 ; B3(u8): tg1 -> tg2
static constexpr size_t BUFB   = (size_t)100032*DP*2;   // 64,020,480
static constexpr size_t BUFU8  = (size_t)100032*DP;     // 32,010,240
static constexpr size_t OFF_B0    = 0;
static constexpr size_t OFF_B1    = BUFB;
static constexpr size_t OFF_B2    = 2*BUFB;
static constexpr size_t OFF_B3    = 3*BUFB;
static constexpr size_t OFF_RFWD  = OFF_B3 + BUFU8;           // R*640*2 bf16
static constexpr size_t OFF_WTKG  = OFF_RFWD + 2400000;
static constexpr size_t OFF_WTW1  = OFF_WTKG + 204800;
static constexpr size_t OFF_WTW2  = OFF_WTW1 + 204800;
static constexpr size_t OFF_WTDN  = OFF_WTW2 + 204800;        // [320,960] bf16 transposed
static constexpr size_t OFF_BIASP = OFF_WTDN + 614400;
static constexpr size_t OFF_BGP   = OFF_BIASP + 1280;
static constexpr size_t OFF_PTRHR = OFF_BGP + 1280;
static constexpr size_t OFF_PTRTR = OFF_PTRHR + 4096;
static constexpr size_t OFF_PTRER = OFF_PTRTR + 4096;
static constexpr size_t OFF_PTRADJ= OFF_PTRER + 400896;
static constexpr size_t OFF_CURHR = OFF_PTRADJ + 400896;      // cursors contiguous: 1 memset
static constexpr size_t OFF_CURTR = OFF_CURHR + 4096;
static constexpr size_t OFF_CURER = OFF_CURTR + 4096;
static constexpr size_t OFF_CURADJ= OFF_CURER + 400896;
static constexpr size_t SZ_CURALL = 4096+4096+400896+400896;
static constexpr size_t OFF_SCHR  = OFF_CURADJ + 400896;
static constexpr size_t OFF_SVHR  = OFF_SCHR + 1200000;
static constexpr size_t OFF_SCTR  = OFF_SVHR + 1200000;
static constexpr size_t OFF_SVTR  = OFF_SCTR + 1200000;
static constexpr size_t OFF_SCER  = OFF_SVTR + 1200000;
static constexpr size_t OFF_SVER  = OFF_SCER + 1200000;
static constexpr size_t OFF_SCADJ = OFF_SVER + 1200000;
static constexpr size_t OFF_SVADJ = OFF_SCADJ + 2400000;
static constexpr size_t OFF_PART  = OFF_SVADJ + 2400000;
static constexpr size_t OFF_BSUM  = OFF_PART + 40000;
// total ~241.4 MB

// ---------------- weight prep ----------------
__global__ void k_prep_sq(const float* kg, const float* w1, const float* w2,
                          unsigned short* wtKG, unsigned short* wtW1, unsigned short* wtW2){
  int n = blockIdx.x, which = blockIdx.y, k = threadIdx.x;
  const float* src = which==0 ? kg : (which==1 ? w1 : w2);
  unsigned short* dst = which==0 ? wtKG : (which==1 ? wtW1 : wtW2);
  float v = (n < D_N && k < D_N) ? src[k*D_N + n] : 0.f;
  dst[(size_t)n*DP + k] = f2bf(v);
}

// DenseP_t[n][k]: k<300 -> Dense[k][n]; 320<=k<920 -> Dense[k-20][n]; else 0
__global__ void k_prep_dense(const float* dn, unsigned short* wt){
  int n = blockIdx.x, t = threadIdx.x;
  for(int k=t; k<KD; k+=320){
    int ko = (k < D_N) ? k : ((k >= DP && k < 920) ? k-20 : -1);
    float v = (n < D_N && ko >= 0) ? dn[(size_t)ko*D_N + n] : 0.f;
    wt[(size_t)n*KD + k] = f2bf(v);
  }
}

__global__ void k_prep_bias(const float* bias, const float* bg, float* biasP, float* bgP){
  int t = threadIdx.x;
  biasP[t] = (t < D_N) ? bias[t] : 0.f;
  bgP[t]   = (t < D_N) ? bg[t]   : 0.f;
}

// ---------------- emb normalize -> bf16 padded (wave-per-row, float4) ----------------
__global__ __launch_bounds__(256) void k_normalize(const float* __restrict__ w,
                                                   unsigned short* __restrict__ embb){
  int wv = threadIdx.x >> 6, lane = threadIdx.x & 63;
  int e = blockIdx.x*4 + wv;                      // grid = E/4
  const float4* row = (const float4*)(w + (size_t)e*D_N);
  float4 x0 = row[lane];
  float4 x1 = make_float4(0.f,0.f,0.f,0.f);
  if(lane < 11) x1 = row[64 + lane];
  float s = x0.x*x0.x + x0.y*x0.y + x0.z*x0.z + x0.w*x0.w
          + x1.x*x1.x + x1.y*x1.y + x1.z*x1.z + x1.w*x1.w;
  #pragma unroll
  for(int off=32; off; off>>=1) s += __shfl_xor(s, off);
  float rn = rsqrtf(s);
  unsigned short* orow = embb + (size_t)e*DP;
  uint2 o0; o0.x = pack2(x0.x*rn, x0.y*rn); o0.y = pack2(x0.z*rn, x0.w*rn);
  *(uint2*)(orow + lane*4) = o0;
  if(lane < 16){
    uint2 o1 = make_uint2(0u,0u);
    if(lane < 11){ o1.x = pack2(x1.x*rn, x1.y*rn); o1.y = pack2(x1.z*rn, x1.w*rn); }
    *(uint2*)(orow + 256 + lane*4) = o1;
  }
}

// ---------------- CSR build (counting sort) ----------------
__global__ void k_count(const int* hr, const int* tr, const int* er, const int* ad,
                        int* cHR, int* cTR, int* cER, int* cAD){
  int i = blockIdx.x*256 + threadIdx.x;
  if(i < 300000)       atomicAdd(&cHR[hr[i]], 1);
  else if(i < 600000)  atomicAdd(&cTR[tr[i-300000]], 1);
  else if(i < 900000)  atomicAdd(&cER[er[i-600000]], 1);
  else if(i < 1500000) atomicAdd(&cAD[ad[i-900000]], 1);
}

__global__ void k_scan_small(int* cHR, int* cTR, int* pHR, int* pTR){
  __shared__ int s[1024];
  int t = threadIdx.x;
  for(int w=0; w<2; w++){
    int* cnt = w ? cTR : cHR; int* ptr = w ? pTR : pHR;
    int c = (t < R_N) ? cnt[t] : 0;
    s[t] = c; __syncthreads();
    for(int off=1; off<1024; off<<=1){
      int v = (t>=off) ? s[t-off] : 0; __syncthreads();
      s[t] += v; __syncthreads();
    }
    int excl = s[t] - c;
    if(t < R_N){ ptr[t] = excl; cnt[t] = excl; }
    if(t == R_N-1) ptr[R_N] = s[t];
    __syncthreads();
  }
}

__global__ void k_scan_part(const int* cER, const int* cAD, int* pER, int* pAD, int* bsum){
  int which = blockIdx.y;
  const int* cnt = which ? cAD : cER;
  int* ptr = which ? pAD : pER;
  __shared__ int s[1024];
  int g = blockIdx.x, t = threadIdx.x, i = g*1024 + t;
  int c = (i < E_N) ? cnt[i] : 0;
  s[t] = c; __syncthreads();
  for(int off=1; off<1024; off<<=1){
    int v = (t>=off) ? s[t-off] : 0; __syncthreads();
    s[t] += v; __syncthreads();
  }
  if(i < E_N) ptr[i] = s[t] - c;
  if(t == 1023) bsum[which*128 + g] = s[1023];
}

__global__ void k_scan_mid(int* bsum, int* pER, int* pAD){
  __shared__ int s[128];
  int t = threadIdx.x;
  for(int w=0; w<2; w++){
    int v = (t < 98) ? bsum[w*128 + t] : 0;
    s[t] = v; __syncthreads();
    for(int off=1; off<128; off<<=1){
      int u = (t>=off) ? s[t-off] : 0; __syncthreads();
      s[t] += u; __syncthreads();
    }
    if(t < 98) bsum[w*128 + t] = s[t] - v;
    if(t == 97){ int* p = w ? pAD : pER; p[E_N] = s[97]; }
    __syncthreads();
  }
}

__global__ void k_scan_add(const int* bsum, int* pER, int* pAD, int* curER, int* curAD){
  int which = blockIdx.y;
  int* ptr = which ? pAD : pER;
  int* cur = which ? curAD : curER;
  int g = blockIdx.x, i = g*1024 + threadIdx.x;
  if(i < E_N){ int v = ptr[i] + bsum[which*128 + g]; ptr[i] = v; cur[i] = v; }
}

__global__ void k_scatter(const int* hr_r, const int* hr_c, const float* hr_v,
                          const int* tr_r, const int* tr_c, const float* tr_v,
                          const int* er_r, const int* er_c, const float* er_v,
                          const int* ad_r, const int* ad_c, const float* ad_v,
                          int* cHR, int* cTR, int* cER, int* cAD,
                          int* scHR, float* svHR, int* scTR, float* svTR,
                          int* scER, float* svER, int* scAD, float* svAD){
  int i = blockIdx.x*256 + threadIdx.x;
  if(i < 300000){ int p=atomicAdd(&cHR[hr_r[i]],1); scHR[p]=hr_c[i]; svHR[p]=hr_v[i]; }
  else if(i < 600000){ int j=i-300000; int p=atomicAdd(&cTR[tr_r[j]],1); scTR[p]=tr_c[j]; svTR[p]=tr_v[j]; }
  else if(i < 900000){ int j=i-600000; int p=atomicAdd(&cER[er_r[j]],1); scER[p]=er_c[j]; svER[p]=er_v[j]; }
  else if(i < 1500000){ int j=i-900000; int p=atomicAdd(&cAD[ad_r[j]],1); scAD[p]=ad_c[j]; svAD[p]=ad_v[j]; }
}

// ---------------- spmm rel (CSR per-row) ----------------
__global__ __launch_bounds__(256) void k_spmm_rel(
    const int* __restrict__ ptr, const int* __restrict__ scol, const float* __restrict__ sval,
    const unsigned short* __restrict__ embb, unsigned short* __restrict__ rfwdb, int off){
  int w = threadIdx.x >> 6, lane = threadIdx.x & 63;
  int r = blockIdx.x*2 + (w>>1);
  int half = w & 1;
  int elem = half*160 + 4*lane;
  bool act = (lane < 40) && (elem < 300);
  int b = ptr[r], e2 = ptr[r+1];
  float a0=0.f, a1=0.f, a2=0.f, a3=0.f;
  if(act){
    const unsigned short* base = embb + elem;
    int j = b;
    for(; j+4 <= e2; j += 4){
      int c0=scol[j], c1=scol[j+1], c2=scol[j+2], c3=scol[j+3];
      float v0=sval[j], v1=sval[j+1], v2=sval[j+2], v3=sval[j+3];
      uint2 x0 = *(const uint2*)(base + (size_t)c0*DP);
      uint2 x1 = *(const uint2*)(base + (size_t)c1*DP);
      uint2 x2 = *(const uint2*)(base + (size_t)c2*DP);
      uint2 x3 = *(const uint2*)(base + (size_t)c3*DP);
      a0 += v0*bf2f(x0.x&0xFFFF) + v1*bf2f(x1.x&0xFFFF) + v2*bf2f(x2.x&0xFFFF) + v3*bf2f(x3.x&0xFFFF);
      a1 += v0*bf2f(x0.x>>16)    + v1*bf2f(x1.x>>16)    + v2*bf2f(x2.x>>16)    + v3*bf2f(x3.x>>16);
      a2 += v0*bf2f(x0.y&0xFFFF) + v1*bf2f(x1.y&0xFFFF) + v2*bf2f(x2.y&0xFFFF) + v3*bf2f(x3.y&0xFFFF);
      a3 += v0*bf2f(x0.y>>16)    + v1*bf2f(x1.y>>16)    + v2*bf2f(x2.y>>16)    + v3*bf2f(x3.y>>16);
    }
    for(; j < e2; j++){
      int c = scol[j]; float v = sval[j];
      uint2 x = *(const uint2*)(base + (size_t)c*DP);
      a0 += v*bf2f(x.x&0xFFFF); a1 += v*bf2f(x.x>>16);
      a2 += v*bf2f(x.y&0xFFFF); a3 += v*bf2f(x.y>>16);
    }
    uint2 o;
    o.x = pack2(a0, a1);
    o.y = pack2(a2, a3);
    *(uint2*)&rfwdb[(size_t)r*640 + off + elem] = o;
  }
}

// ---------------- fused adj-spmm + highway ----------------
// out[e] = tg*relu(sum val*hw[col]) + (1-tg)*res[e];  tg from u8 gate buffer
__global__ __launch_bounds__(256) void k_spmm_hw(
    const int* __restrict__ ptr, const int* __restrict__ scol, const float* __restrict__ sval,
    const unsigned short* __restrict__ hw, const unsigned char* __restrict__ tg,
    const unsigned short* __restrict__ res, unsigned short* __restrict__ out){
  int w = threadIdx.x >> 6, lane = threadIdx.x & 63;
  int e = blockIdx.x*4 + w;
  int b = ptr[e], en = ptr[e+1];
  if(lane < 40){
    float a0[8], a1[8];
    #pragma unroll
    for(int i=0;i<8;i++){ a0[i]=0.f; a1[i]=0.f; }
    const unsigned short* base = hw + lane*8;
    int j = b;
    for(; j+2 <= en; j += 2){
      int c0 = scol[j], c1 = scol[j+1];
      float v0 = sval[j], v1 = sval[j+1];
      bf16x8 x0 = *(const bf16x8*)(base + (size_t)c0*DP);
      bf16x8 x1 = *(const bf16x8*)(base + (size_t)c1*DP);
      #pragma unroll
      for(int i=0;i<8;i++){ a0[i] += v0 * bf2f((unsigned short)x0[i]);
                            a1[i] += v1 * bf2f((unsigned short)x1[i]); }
    }
    if(j < en){
      int c = scol[j]; float v = sval[j];
      bf16x8 x = *(const bf16x8*)(base + (size_t)c*DP);
      #pragma unroll
      for(int i=0;i<8;i++) a0[i] += v * bf2f((unsigned short)x[i]);
    }
    uint2 tu = *(const uint2*)(tg + (size_t)e*DP + lane*8);
    bf16x8 rv = *(const bf16x8*)(res + (size_t)e*DP + lane*8);
    bf16x8 o;
    #pragma unroll
    for(int i=0;i<8;i++){
      unsigned int word = (i<4) ? tu.x : tu.y;
      float g = (float)((word >> ((i&3)*8)) & 255u);
      g = (g + 0.5f) * 0.00390625f;
      float gcn = fmaxf(a0[i]+a1[i], 0.f);
      o[i] = (short)f2bf(g*gcn + (1.f-g)*bf2f(rv[i]));
    }
    *(bf16x8*)&out[(size_t)e*DP + lane*8] = o;
  }
}

// ---------------- fused MFMA GEMM ----------------
// XOR-swizzled LDS tiles (chunk ^= row&7), zero bank conflict pattern (proven R4).
__device__ __forceinline__ void stageA(unsigned short (*buf)[DP],
                                       const unsigned short* __restrict__ src, int tid){
  #pragma unroll
  for(int i=0; i<10; i++){
    int idx = tid + i*256;
    int row = idx/40, colc = idx%40;
    *(uint4*)&buf[row][(colc ^ (row&7))*8] = *(const uint4*)(src + (size_t)idx*8);
  }
}
__device__ __forceinline__ void storeT(unsigned short* __restrict__ dst,
                                       const unsigned short (*buf)[DP], int tid){
  #pragma unroll
  for(int i=0; i<10; i++){
    int idx = tid + i*256;
    int row = idx/40, colc = idx%40;
    *(uint4*)(dst + (size_t)idx*8) = *(const uint4*)&buf[row][(colc ^ (row&7))*8];
  }
}
// single place computing all MFMA operand addresses (R5 lesson: no double-offset)
__device__ __forceinline__ void kloop(f32x4 acc[4][5], const unsigned short (*As)[DP],
    const unsigned short* __restrict__ Bt, int Kp, int kb, int wave, int quad, int l16){
  #pragma unroll 2
  for(int kk=0; kk<DP; kk+=32){
    bf16x8 af[4], bfr[5];
    #pragma unroll
    for(int mf=0; mf<4; mf++)
      af[mf] = *(const bf16x8*)&As[mf*16 + l16][(((kk>>3)+quad) ^ (l16&7))*8];
    #pragma unroll
    for(int nf=0; nf<5; nf++)
      bfr[nf] = *(const bf16x8*)(Bt + (size_t)(wave*80 + nf*16 + l16)*Kp + kb + kk + quad*8);
    #pragma unroll
    for(int mf=0; mf<4; mf++)
      #pragma unroll
      for(int nf=0; nf<5; nf++)
        acc[mf][nf] = __builtin_amdgcn_mfma_f32_16x16x32_bf16(af[mf], bfr[nf], acc[mf][nf], 0, 0, 0);
  }
}

// dense=1: A=emb; nb built from er-CSR; h=emb+relu([emb|nb]@Dense+bias) -> hOut AND LDS;
//          then chained h@W1 -> hwOut, sigmoid(h@KG+bg) -> u8 tgOut.
// dense=0: A=hg1 (staged); hg1@W2 -> hwOut, sigmoid(hg1@KG+bg) -> tgOut.
__global__ __launch_bounds__(256,2) void k_gemm_f(
    const unsigned short* __restrict__ Ain,
    const unsigned short* __restrict__ BtD,
    const int* __restrict__ erPtr, const int* __restrict__ erCol, const float* __restrict__ erVal,
    const unsigned short* __restrict__ rfwdb,
    const float* __restrict__ biasP,
    const unsigned short* __restrict__ BtW,
    const unsigned short* __restrict__ BtG,
    const float* __restrict__ bgP,
    unsigned short* __restrict__ hOut,
    unsigned short* __restrict__ hwOut,
    unsigned char*  __restrict__ tgOut,
    int dense){
  __shared__ unsigned short buf0[BM][DP];   // 40KB
  __shared__ unsigned short buf1[BM][DP];   // 40KB -> 2 blocks/CU
  int tid = threadIdx.x;
  int wave = tid>>6, lane = tid&63, quad = lane>>4, l16 = lane&15;
  int m0 = blockIdx.x * BM;

  stageA(buf0, Ain + (size_t)m0*DP, tid);
  __syncthreads();

  unsigned short (*chain)[DP] = buf0;       // A operand for chained W/KG GEMMs
  unsigned short (*scratch)[DP] = buf1;     // epilogue transpose space

  if(dense){
    float breg[5];
    #pragma unroll
    for(int nf=0; nf<5; nf++) breg[nf] = biasP[wave*80 + nf*16 + l16];
    f32x4 acc[4][5];
    #pragma unroll
    for(int mf=0; mf<4; mf++)
      #pragma unroll
      for(int nf=0; nf<5; nf++) acc[mf][nf] = (f32x4){0.f,0.f,0.f,0.f};
    // two nb halves built into buf1 from er-CSR gathers of L2-resident rfwdb
    for(int h=0; h<2; h++){
      if(h) __syncthreads();                // protect buf1 before rebuild
      int halfOff = h*320;
      for(int rr=0; rr<16; rr++){
        int row = wave*16 + rr;
        int e = m0 + row;
        float a0[8], a1[8];
        #pragma unroll
        for(int i=0;i<8;i++){ a0[i]=0.f; a1[i]=0.f; }
        if(e < E_N && lane < 40){
          int jb = erPtr[e], je = erPtr[e+1];
          const unsigned short* gb = rfwdb + halfOff + lane*8;
          int j = jb;
          for(; j+2 <= je; j += 2){
            int c0=erCol[j], c1=erCol[j+1];
            float v0=erVal[j], v1=erVal[j+1];
            int p0=c0, p1=c1;
            if(c0 >= R_N){ p0 = c0-R_N; v0 = -v0; }
            if(c1 >= R_N){ p1 = c1-R_N; v1 = -v1; }
            bf16x8 x0 = *(const bf16x8*)(gb + (size_t)p0*640);
            bf16x8 x1 = *(const bf16x8*)(gb + (size_t)p1*640);
            #pragma unroll
            for(int i=0;i<8;i++){ a0[i] += v0*bf2f((unsigned short)x0[i]);
                                  a1[i] += v1*bf2f((unsigned short)x1[i]); }
          }
          if(j < je){
            int c=erCol[j]; float v=erVal[j];
            int p=c; if(c >= R_N){ p = c-R_N; v = -v; }
            bf16x8 x = *(const bf16x8*)(gb + (size_t)p*640);
            #pragma unroll
            for(int i=0;i<8;i++) a0[i] += v*bf2f((unsigned short)x[i]);
          }
        }
        if(lane < 40){
          bf16x8 o;
          #pragma unroll
          for(int i=0;i<8;i++) o[i] = (short)f2bf(a0[i]+a1[i]);
          *(bf16x8*)&buf1[row][(lane ^ (row&7))*8] = o;
        }
      }
      __syncthreads();
      kloop(acc, buf1, BtD, KD, DP + halfOff, wave, quad, l16);
    }
    kloop(acc, buf0, BtD, KD, 0, wave, quad, l16);
    __syncthreads();                        // all buf1 reads done before h written
    // epilogue: h = emb + relu(acc+bias); residual from buf0; h -> buf1 (C->A transpose)
    #pragma unroll
    for(int mf=0; mf<4; mf++){
      #pragma unroll
      for(int nf=0; nf<5; nf++){
        int col = wave*80 + nf*16 + l16;
        #pragma unroll
        for(int i=0; i<4; i++){
          int rowl = mf*16 + quad*4 + i;
          int a = ((col>>3) ^ (rowl&7))*8 + (col&7);
          float resv = bf2f(buf0[rowl][a]);
          buf1[rowl][a] = f2bf(resv + fmaxf(acc[mf][nf][i] + breg[nf], 0.f));
        }
      }
    }
    __syncthreads();
    storeT(hOut + (size_t)m0*DP, buf1, tid);   // coalesced h write
    chain = buf1; scratch = buf0;
  }

  // chained GEMM 1: chain @ BtW -> hwOut (coalesced via scratch)
  {
    f32x4 acc[4][5];
    #pragma unroll
    for(int mf=0; mf<4; mf++)
      #pragma unroll
      for(int nf=0; nf<5; nf++) acc[mf][nf] = (f32x4){0.f,0.f,0.f,0.f};
    kloop(acc, chain, BtW, DP, 0, wave, quad, l16);
    // scratch free: dense -> buf0 last read at residual (pre-barrier); else buf1 unused
    #pragma unroll
    for(int mf=0; mf<4; mf++){
      #pragma unroll
      for(int nf=0; nf<5; nf++){
        int col = wave*80 + nf*16 + l16;
        #pragma unroll
        for(int i=0; i<4; i++){
          int rowl = mf*16 + quad*4 + i;
          scratch[rowl][((col>>3) ^ (rowl&7))*8 + (col&7)] = f2bf(acc[mf][nf][i]);
        }
      }
    }
    __syncthreads();
    storeT(hwOut + (size_t)m0*DP, scratch, tid);
  }

  // chained GEMM 2: gate = sigmoid(chain @ BtG + bg) -> u8 tgOut (coalesced via scratch-as-u8)
  {
    float greg[5];
    #pragma unroll
    for(int nf=0; nf<5; nf++) greg[nf] = bgP[wave*80 + nf*16 + l16];
    f32x4 acc[4][5];
    #pragma unroll
    for(int mf=0; mf<4; mf++)
      #pragma unroll
      for(int nf=0; nf<5; nf++) acc[mf][nf] = (f32x4){0.f,0.f,0.f,0.f};
    kloop(acc, chain, BtG, DP, 0, wave, quad, l16);
    __syncthreads();                        // hw stores' scratch reads done
    unsigned char* bu = (unsigned char*)scratch;
    #pragma unroll
    for(int mf=0; mf<4; mf++){
      #pragma unroll
      for(int nf=0; nf<5; nf++){
        int col = wave*80 + nf*16 + l16;
        #pragma unroll
        for(int i=0; i<4; i++){
          int rowl = mf*16 + quad*4 + i;
          float tg = 1.f / (1.f + expf(-(acc[mf][nf][i] + greg[nf])));
          int u = (int)(tg * 256.f);
          u = u < 0 ? 0 : (u > 255 ? 255 : u);
          bu[rowl*DP + col] = (unsigned char)u;
        }
      }
    }
    __syncthreads();
    unsigned char* dst = tgOut + (size_t)m0*DP;
    #pragma unroll
    for(int i=0; i<5; i++){
      int idx = tid + i*256;                // 1280 x 16B = 20KB
      *(uint4*)(dst + (size_t)idx*16) = *(const uint4*)(bu + (size_t)idx*16);
    }
  }
}

// ---------------- loss (dm fused; 2-way k interleave) ----------------
__global__ __launch_bounds__(256) void k_loss(const unsigned short* __restrict__ node,
                       const int* __restrict__ pl, const int* __restrict__ pr,
                       const int* __restrict__ nr, const int* __restrict__ nl,
                       const float* __restrict__ mask,
                       float* __restrict__ part){
  int t = blockIdx.x;
  int w = threadIdx.x >> 6, lane = threadIdx.x & 63;
  __shared__ float wsum[4];
  bool act = lane < 40;
  size_t lb = (size_t)pl[t]*DP, rb = (size_t)pr[t]*DP;
  float lv[8], rv[8];
  #pragma unroll
  for(int i=0;i<8;i++){ lv[i]=0.f; rv[i]=0.f; }
  if(act){
    bf16x8 L = *(const bf16x8*)&node[lb + lane*8];
    bf16x8 R = *(const bf16x8*)&node[rb + lane*8];
    #pragma unroll
    for(int i=0;i<8;i++){ lv[i]=bf2f((unsigned short)L[i]); rv[i]=bf2f((unsigned short)R[i]); }
  }
  float s = 0.f;
  #pragma unroll
  for(int i=0;i<8;i++) s += fabsf(lv[i] - rv[i]);
  #pragma unroll
  for(int off=32; off; off>>=1) s += __shfl_xor(s, off);
  float dm = s + 1.0f;   // + GAMMA

  float local = 0.f;
  for(int k=w; k<K_N; k+=8){
    int k2 = k + 4;
    bool h2 = k2 < K_N;
    int kb = h2 ? k2 : k;
    float s1a=0.f, s2a=0.f, s1b=0.f, s2b=0.f;
    if(act){
      size_t nrb  = (size_t)nr[t*K_N+k ]*DP, nlb  = (size_t)nl[t*K_N+k ]*DP;
      size_t nrb2 = (size_t)nr[t*K_N+kb]*DP, nlb2 = (size_t)nl[t*K_N+kb]*DP;
      bf16x8 X1 = *(const bf16x8*)&node[nrb  + lane*8];
      bf16x8 Y1 = *(const bf16x8*)&node[nlb  + lane*8];
      bf16x8 X2 = *(const bf16x8*)&node[nrb2 + lane*8];
      bf16x8 Y2 = *(const bf16x8*)&node[nlb2 + lane*8];
      #pragma unroll
      for(int i=0;i<8;i++){
        s1a += fabsf(lv[i] - bf2f((unsigned short)X1[i]));
        s2a += fabsf(bf2f((unsigned short)Y1[i]) - rv[i]);
        s1b += fabsf(lv[i] - bf2f((unsigned short)X2[i]));
        s2b += fabsf(bf2f((unsigned short)Y2[i]) - rv[i]);
      }
    }
    #pragma unroll
    for(int off=32; off; off>>=1){
      s1a += __shfl_xor(s1a, off); s2a += __shfl_xor(s2a, off);
      s1b += __shfl_xor(s1b, off); s2b += __shfl_xor(s2b, off);
    }
    if(lane==0){
      local += (fmaxf(dm - s1a, 0.f) + fmaxf(dm - s2a, 0.f)) * mask[t*K_N+k];
      if(h2) local += (fmaxf(dm - s1b, 0.f) + fmaxf(dm - s2b, 0.f)) * mask[t*K_N+k2];
    }
  }
  if(lane==0) wsum[w] = local;
  __syncthreads();
  if(threadIdx.x==0) part[t] = wsum[0]+wsum[1]+wsum[2]+wsum[3];
}

__global__ void k_reduce(const float* part, float* out){
  __shared__ float s[256];
  int t = threadIdx.x;
  float a = 0.f;
  for(int i=t; i<T_N; i+=256) a += part[i];
  s[t] = a; __syncthreads();
  for(int off=128; off; off>>=1){ if(t<off) s[t]+=s[t+off]; __syncthreads(); }
  if(t==0) out[0] = s[0]*0.5f;
}

// ---------------- driver ----------------
extern "C" void kernel_launch(void* const* d_in, const int* in_sizes, int n_in,
                              void* d_out, int out_size, void* d_ws, size_t ws_size,
                              hipStream_t stream){
  const float* Wemb = (const float*)d_in[0];
  const float* KG   = (const float*)d_in[1];
  const float* BG   = (const float*)d_in[2];
  const float* W1   = (const float*)d_in[3];
  const float* W2   = (const float*)d_in[4];
  const float* DN   = (const float*)d_in[5];
  const float* BI   = (const float*)d_in[6];
  const int* HRr = (const int*)d_in[7];  const int* HRc = (const int*)d_in[8];  const float* HRv = (const float*)d_in[9];
  const int* TRr = (const int*)d_in[10]; const int* TRc = (const int*)d_in[11]; const float* TRv = (const float*)d_in[12];
  const int* ERr = (const int*)d_in[13]; const int* ERc = (const int*)d_in[14]; const float* ERv = (const float*)d_in[15];
  const int* ADr = (const int*)d_in[16]; const int* ADc = (const int*)d_in[17]; const float* ADv = (const float*)d_in[18];
  const int* PL = (const int*)d_in[19]; const int* PR = (const int*)d_in[20];
  const int* NR = (const int*)d_in[21]; const int* NL = (const int*)d_in[22];
  const float* MASK = (const float*)d_in[23];
  char* ws = (char*)d_ws;

  unsigned short* B0 = (unsigned short*)(ws + OFF_B0);   // emb -> hg1
  unsigned short* B1 = (unsigned short*)(ws + OFF_B1);   // h -> node
  unsigned short* B2 = (unsigned short*)(ws + OFF_B2);   // hw1 -> hw2
  unsigned char*  B3 = (unsigned char*)(ws + OFF_B3);    // tg1 -> tg2 (u8)
  unsigned short* rfwdb = (unsigned short*)(ws + OFF_RFWD);
  unsigned short* wtKG = (unsigned short*)(ws + OFF_WTKG);
  unsigned short* wtW1 = (unsigned short*)(ws + OFF_WTW1);
  unsigned short* wtW2 = (unsigned short*)(ws + OFF_WTW2);
  unsigned short* wtDN = (unsigned short*)(ws + OFF_WTDN);
  float* biasP = (float*)(ws + OFF_BIASP);
  float* bgP   = (float*)(ws + OFF_BGP);
  int* pHR = (int*)(ws + OFF_PTRHR); int* pTR = (int*)(ws + OFF_PTRTR);
  int* pER = (int*)(ws + OFF_PTRER); int* pAD = (int*)(ws + OFF_PTRADJ);
  int* cHR = (int*)(ws + OFF_CURHR); int* cTR = (int*)(ws + OFF_CURTR);
  int* cER = (int*)(ws + OFF_CURER); int* cAD = (int*)(ws + OFF_CURADJ);
  int* scHR = (int*)(ws + OFF_SCHR); float* svHR = (float*)(ws + OFF_SVHR);
  int* scTR = (int*)(ws + OFF_SCTR); float* svTR = (float*)(ws + OFF_SVTR);
  int* scER = (int*)(ws + OFF_SCER); float* svER = (float*)(ws + OFF_SVER);
  int* scAD = (int*)(ws + OFF_SCADJ); float* svAD = (float*)(ws + OFF_SVADJ);
  float* part = (float*)(ws + OFF_PART);
  int* bsum   = (int*)(ws + OFF_BSUM);

  (void)hipMemsetAsync(ws + OFF_CURHR, 0, SZ_CURALL, stream);
  (void)hipMemsetAsync(ws + OFF_RFWD, 0, 1280000, stream);

  k_prep_sq<<<dim3(320,3), 320, 0, stream>>>(KG, W1, W2, wtKG, wtW1, wtW2);
  k_prep_dense<<<320, 320, 0, stream>>>(DN, wtDN);
  k_prep_bias<<<1, 320, 0, stream>>>(BI, BG, biasP, bgP);
  k_normalize<<<E_N/4, 256, 0, stream>>>(Wemb, B0);

  k_count<<<5860, 256, 0, stream>>>(HRr, TRr, ERr, ADr, cHR, cTR, cER, cAD);
  k_scan_small<<<1, 1024, 0, stream>>>(cHR, cTR, pHR, pTR);
  k_scan_part<<<dim3(98,2), 1024, 0, stream>>>(cER, cAD, pER, pAD, bsum);
  k_scan_mid<<<1, 128, 0, stream>>>(bsum, pER, pAD);
  k_scan_add<<<dim3(98,2), 1024, 0, stream>>>(bsum, pER, pAD, cER, cAD);
  k_scatter<<<5860, 256, 0, stream>>>(HRr,HRc,HRv, TRr,TRc,TRv, ERr,ERc,ERv, ADr,ADc,ADv,
                                      cHR,cTR,cER,cAD, scHR,svHR, scTR,svTR, scER,svER, scAD,svAD);

  k_spmm_rel<<<R_N/2, 256, 0, stream>>>(pHR, scHR, svHR, B0, rfwdb, 0);
  k_spmm_rel<<<R_N/2, 256, 0, stream>>>(pTR, scTR, svTR, B0, rfwdb, 300);

  // Pass 1 (fused): h = emb + relu([emb|nb]@Dense+Bias) -> B1 ; hw1 = h@W1 -> B2 ;
  //                 tg1 = sigmoid(h@KG+bg) -> B3(u8)
  k_gemm_f<<<NT, 256, 0, stream>>>(B0, wtDN, pER, scER, svER, rfwdb, biasP,
                                   wtW1, wtKG, bgP, B1, B2, B3, 1);
  // S1 (fused): hg1 = tg1*relu(adj@hw1) + (1-tg1)*h -> B0
  k_spmm_hw<<<E_N/4, 256, 0, stream>>>(pAD, scAD, svAD, B2, B3, B1, B0);
  // Pass 2 (fused): hw2 = hg1@W2 -> B2 ; tg2 = sigmoid(hg1@KG+bg) -> B3
  k_gemm_f<<<NT, 256, 0, stream>>>(B0, nullptr, nullptr, nullptr, nullptr, nullptr, nullptr,
                                   wtW2, wtKG, bgP, nullptr, B2, B3, 0);
  // S2 (fused): node = tg2*relu(adj@hw2) + (1-tg2)*hg1 -> B1
  k_spmm_hw<<<E_N/4, 256, 0, stream>>>(pAD, scAD, svAD, B2, B3, B0, B1);

  k_loss<<<T_N, 256, 0, stream>>>(B1, PL, PR, NR, NL, MASK, part);
  k_reduce<<<1, 256, 0, stream>>>(part, (float*)d_out);
}